// Round 1
// baseline (556.044 us; speedup 1.0000x reference)
//
#include <hip/hip_runtime.h>
#include <hip/hip_bf16.h>

#define NHEADS 4
#define ODIM 32
#define CDIM 128   // NHEADS*ODIM
#define KDIM 128   // IN_DIM

// ---------------- CSR build ----------------

__global__ void k_init_counts(int* counts, int N) {
    int i = blockIdx.x * blockDim.x + threadIdx.x;
    if (i < N) counts[i] = 1;   // self loop
}

__global__ void k_count(const int* __restrict__ ei, int E, int* counts) {
    int i = blockIdx.x * blockDim.x + threadIdx.x;
    if (i < E) {
        // forward edge (s0 -> d0): dst = d0 ; reverse edge: dst = s0
        atomicAdd(&counts[ei[E + i]], 1);
        atomicAdd(&counts[ei[i]], 1);
    }
}

// block b sums counts[b*1024 .. b*1024+1024)
__global__ void k_bsum(const int* __restrict__ counts, int* bsums, int N) {
    __shared__ int ws[4];
    int tid = threadIdx.x;
    int base = blockIdx.x * 1024 + tid * 4;
    int s = 0;
    #pragma unroll
    for (int i = 0; i < 4; ++i) s += (base + i < N) ? counts[base + i] : 0;
    #pragma unroll
    for (int off = 1; off < 64; off <<= 1) s += __shfl_xor(s, off, 64);
    if ((tid & 63) == 0) ws[tid >> 6] = s;
    __syncthreads();
    if (tid == 0) bsums[blockIdx.x] = ws[0] + ws[1] + ws[2] + ws[3];
}

__global__ void k_tops(int* bsums, int NB) {
    if (threadIdx.x == 0) {
        int run = 0;
        for (int i = 0; i < NB; ++i) { int t = bsums[i]; bsums[i] = run; run += t; }
    }
}

__global__ void k_scan_add(const int* __restrict__ counts, const int* __restrict__ btops,
                           int* row_start, int* cursor, int N, int Ea) {
    __shared__ int wsum[4];
    int tid = threadIdx.x;
    int b = blockIdx.x;
    int base = b * 1024 + tid * 4;
    int v[4];
    #pragma unroll
    for (int i = 0; i < 4; ++i) v[i] = (base + i < N) ? counts[base + i] : 0;
    int tsum = v[0] + v[1] + v[2] + v[3];
    int lane = tid & 63, w = tid >> 6;
    int sc = tsum;
    #pragma unroll
    for (int off = 1; off < 64; off <<= 1) {
        int o = __shfl_up(sc, off, 64);
        if (lane >= off) sc += o;
    }
    if (lane == 63) wsum[w] = sc;
    __syncthreads();
    int woff = 0;
    for (int i = 0; i < w; ++i) woff += wsum[i];
    int run = btops[b] + woff + (sc - tsum);
    #pragma unroll
    for (int i = 0; i < 4; ++i) {
        if (base + i < N) { row_start[base + i] = run; cursor[base + i] = run; }
        run += v[i];
    }
    if (b == 0 && tid == 0) row_start[N] = Ea;
}

__global__ void k_scatter(const int* __restrict__ ei, int E, int N,
                          int* cursor, int* colA) {
    int i = blockIdx.x * blockDim.x + threadIdx.x;
    int M = 2 * E + N;
    if (i >= M) return;
    int s, d;
    if (i < E)            { s = ei[i];         d = ei[E + i]; }
    else if (i < 2 * E)   { int j = i - E; s = ei[E + j]; d = ei[j]; }
    else                  { s = i - 2 * E;     d = s; }
    int pos = atomicAdd(&cursor[d], 1);
    colA[pos] = s;
}

// ---------------- projection GEMM + alpha ----------------
// proj = x @ W  (N x 128 x 128), plus alpha_src[n,h], alpha_dst[n,h]
// 256 threads: 8 groups of 32 lanes; group handles 4 nodes; lane j owns cols 4j..4j+3.
__global__ __launch_bounds__(256) void k_proj(
        const float* __restrict__ x, const float* __restrict__ W,
        const float* __restrict__ attn_src, const float* __restrict__ attn_dst,
        float* __restrict__ proj, float* __restrict__ asrc, float* __restrict__ adst,
        int N, int nbatch) {
    __shared__ float Wl[64 * CDIM];          // 32KB: half of W (64 k-rows)
    __shared__ float4 xs4[32][32];           // 16KB: 32 node rows as float4
    int tid = threadIdx.x;
    int g = tid >> 5, j = tid & 31;
    int h = j >> 3;

    for (int batch = blockIdx.x; batch < nbatch; batch += gridDim.x) {
        int base = batch * 32;
        __syncthreads();
        // load 32 x-rows (1024 float4)
        #pragma unroll
        for (int r = 0; r < 4; ++r) {
            int idx = tid + r * 256;
            int row = idx >> 5, kk = idx & 31;
            int n = base + row;
            float4 v = make_float4(0.f, 0.f, 0.f, 0.f);
            if (n < N) v = ((const float4*)x)[(size_t)n * 32 + kk];
            xs4[row][kk] = v;
        }
        float4 acc[4];
        #pragma unroll
        for (int m = 0; m < 4; ++m) acc[m] = make_float4(0.f, 0.f, 0.f, 0.f);

        for (int half = 0; half < 2; ++half) {
            __syncthreads();
            // load 64 k-rows of W (2048 float4)
            #pragma unroll
            for (int r = 0; r < 8; ++r) {
                int idx = tid + r * 256;
                ((float4*)Wl)[idx] = ((const float4*)W)[half * 2048 + idx];
            }
            __syncthreads();
            const float4* Wl4 = (const float4*)Wl;
            #pragma unroll
            for (int k4 = 0; k4 < 16; ++k4) {
                float4 w0 = Wl4[(k4 * 4 + 0) * 32 + j];
                float4 w1 = Wl4[(k4 * 4 + 1) * 32 + j];
                float4 w2 = Wl4[(k4 * 4 + 2) * 32 + j];
                float4 w3 = Wl4[(k4 * 4 + 3) * 32 + j];
                #pragma unroll
                for (int m = 0; m < 4; ++m) {
                    float4 xv = xs4[g * 4 + m][half * 16 + k4];
                    acc[m].x = fmaf(xv.x, w0.x, acc[m].x);
                    acc[m].y = fmaf(xv.x, w0.y, acc[m].y);
                    acc[m].z = fmaf(xv.x, w0.z, acc[m].z);
                    acc[m].w = fmaf(xv.x, w0.w, acc[m].w);
                    acc[m].x = fmaf(xv.y, w1.x, acc[m].x);
                    acc[m].y = fmaf(xv.y, w1.y, acc[m].y);
                    acc[m].z = fmaf(xv.y, w1.z, acc[m].z);
                    acc[m].w = fmaf(xv.y, w1.w, acc[m].w);
                    acc[m].x = fmaf(xv.z, w2.x, acc[m].x);
                    acc[m].y = fmaf(xv.z, w2.y, acc[m].y);
                    acc[m].z = fmaf(xv.z, w2.z, acc[m].z);
                    acc[m].w = fmaf(xv.z, w2.w, acc[m].w);
                    acc[m].x = fmaf(xv.w, w3.x, acc[m].x);
                    acc[m].y = fmaf(xv.w, w3.y, acc[m].y);
                    acc[m].z = fmaf(xv.w, w3.z, acc[m].z);
                    acc[m].w = fmaf(xv.w, w3.w, acc[m].w);
                }
            }
        }
        // epilogue: store proj rows + fused alpha reductions
        float4 as4 = ((const float4*)(attn_src + h * ODIM))[j & 7];
        float4 ad4 = ((const float4*)(attn_dst + h * ODIM))[j & 7];
        #pragma unroll
        for (int m = 0; m < 4; ++m) {
            int n = base + g * 4 + m;
            float ps = acc[m].x * as4.x + acc[m].y * as4.y + acc[m].z * as4.z + acc[m].w * as4.w;
            float pd = acc[m].x * ad4.x + acc[m].y * ad4.y + acc[m].z * ad4.z + acc[m].w * ad4.w;
            ps += __shfl_xor(ps, 1, 8); ps += __shfl_xor(ps, 2, 8); ps += __shfl_xor(ps, 4, 8);
            pd += __shfl_xor(pd, 1, 8); pd += __shfl_xor(pd, 2, 8); pd += __shfl_xor(pd, 4, 8);
            if (n < N) {
                ((float4*)proj)[(size_t)n * 32 + j] = acc[m];
                if ((j & 7) == 0) {
                    asrc[n * 4 + h] = ps;
                    adst[n * 4 + h] = pd;
                }
            }
        }
    }
}

// ---------------- gather / softmax / aggregate ----------------
// 2 nodes per 256-thread block; thread t in [0,128) owns output col t.
__global__ __launch_bounds__(256) void k_gather(
        const float* __restrict__ proj, const float* __restrict__ asrc,
        const float* __restrict__ adst, const int* __restrict__ row_start,
        const int* __restrict__ colA, const float* __restrict__ bias,
        float* __restrict__ out, int N) {
    int node = blockIdx.x * 2 + (threadIdx.x >> 7);
    int t = threadIdx.x & 127;
    if (node >= N) return;
    int h = t >> 5;
    float ad = adst[node * 4 + h];
    int beg = row_start[node];
    int end = row_start[node + 1];
    float denom = 0.f, acc = 0.f;
    for (int e = beg; e < end; ++e) {
        int s = colA[e];
        float as = asrc[s * 4 + h];
        float scv = as + ad;
        scv = (scv > 0.f) ? scv : 0.2f * scv;
        float ex = __expf(scv);
        denom += ex;
        acc = fmaf(ex, proj[(size_t)s * CDIM + t], acc);
    }
    float v = acc / denom + bias[t];
    out[(size_t)node * CDIM + t] = (v > 0.f) ? v : (__expf(v) - 1.f);
}

extern "C" void kernel_launch(void* const* d_in, const int* in_sizes, int n_in,
                              void* d_out, int out_size, void* d_ws, size_t ws_size,
                              hipStream_t stream) {
    const float* x    = (const float*)d_in[0];
    const int*   ei   = (const int*)d_in[1];
    const float* W    = (const float*)d_in[2];
    const float* a_s  = (const float*)d_in[3];
    const float* a_d  = (const float*)d_in[4];
    const float* bias = (const float*)d_in[5];

    int N = in_sizes[0] / KDIM;
    int E = in_sizes[1] / 2;
    int Ea = 2 * E + N;

    char* ws = (char*)d_ws;
    size_t off = 0;
    auto alloc = [&](size_t bytes) -> void* {
        void* p = ws + off;
        off = (off + bytes + 255) & ~(size_t)255;
        return p;
    };
    float* proj      = (float*)alloc((size_t)N * CDIM * 4);
    float* asrc      = (float*)alloc((size_t)N * NHEADS * 4);
    float* adst      = (float*)alloc((size_t)N * NHEADS * 4);
    int*   counts    = (int*)alloc((size_t)N * 4);
    int*   row_start = (int*)alloc((size_t)(N + 1) * 4);
    int*   cursor    = (int*)alloc((size_t)N * 4);
    int*   bsums     = (int*)alloc(4096);
    int*   colA      = (int*)alloc((size_t)Ea * 4);

    int NB = (N + 1023) / 1024;
    int nbatch = (N + 31) / 32;

    k_init_counts<<<(N + 255) / 256, 256, 0, stream>>>(counts, N);
    k_count<<<(E + 255) / 256, 256, 0, stream>>>(ei, E, counts);
    k_bsum<<<NB, 256, 0, stream>>>(counts, bsums, N);
    k_tops<<<1, 64, 0, stream>>>(bsums, NB);
    k_scan_add<<<NB, 256, 0, stream>>>(counts, bsums, row_start, cursor, N, Ea);
    k_scatter<<<(2 * E + N + 255) / 256, 256, 0, stream>>>(ei, E, N, cursor, colA);
    k_proj<<<768, 256, 0, stream>>>(x, W, a_s, a_d, proj, asrc, adst, N, nbatch);
    k_gather<<<(N + 1) / 2, 256, 0, stream>>>(proj, asrc, adst, row_start, colA, bias,
                                              (float*)d_out, N);
}

// Round 2
// 366.287 us; speedup vs baseline: 1.5181x; 1.5181x over previous
//
#include <hip/hip_runtime.h>
#include <hip/hip_bf16.h>

#define NHEADS 4
#define ODIM 32
#define CDIM 128   // NHEADS*ODIM
#define KDIM 128   // IN_DIM

// ---------------- CSR build ----------------

__global__ void k_init_counts(int* counts, int N) {
    int i = blockIdx.x * blockDim.x + threadIdx.x;
    if (i < N) counts[i] = 1;   // self loop
}

__global__ void k_count(const int* __restrict__ ei, int E, int* counts) {
    int i = blockIdx.x * blockDim.x + threadIdx.x;
    if (i < E) {
        atomicAdd(&counts[ei[E + i]], 1);
        atomicAdd(&counts[ei[i]], 1);
    }
}

__global__ void k_bsum(const int* __restrict__ counts, int* bsums, int N) {
    __shared__ int ws[4];
    int tid = threadIdx.x;
    int base = blockIdx.x * 1024 + tid * 4;
    int s = 0;
    #pragma unroll
    for (int i = 0; i < 4; ++i) s += (base + i < N) ? counts[base + i] : 0;
    #pragma unroll
    for (int off = 1; off < 64; off <<= 1) s += __shfl_xor(s, off, 64);
    if ((tid & 63) == 0) ws[tid >> 6] = s;
    __syncthreads();
    if (tid == 0) bsums[blockIdx.x] = ws[0] + ws[1] + ws[2] + ws[3];
}

__global__ void k_tops(int* bsums, int NB) {
    if (threadIdx.x == 0) {
        int run = 0;
        for (int i = 0; i < NB; ++i) { int t = bsums[i]; bsums[i] = run; run += t; }
    }
}

__global__ void k_scan_add(const int* __restrict__ counts, const int* __restrict__ btops,
                           int* row_start, int* cursor, int N, int Ea) {
    __shared__ int wsum[4];
    int tid = threadIdx.x;
    int b = blockIdx.x;
    int base = b * 1024 + tid * 4;
    int v[4];
    #pragma unroll
    for (int i = 0; i < 4; ++i) v[i] = (base + i < N) ? counts[base + i] : 0;
    int tsum = v[0] + v[1] + v[2] + v[3];
    int lane = tid & 63, w = tid >> 6;
    int sc = tsum;
    #pragma unroll
    for (int off = 1; off < 64; off <<= 1) {
        int o = __shfl_up(sc, off, 64);
        if (lane >= off) sc += o;
    }
    if (lane == 63) wsum[w] = sc;
    __syncthreads();
    int woff = 0;
    for (int i = 0; i < w; ++i) woff += wsum[i];
    int run = btops[b] + woff + (sc - tsum);
    #pragma unroll
    for (int i = 0; i < 4; ++i) {
        if (base + i < N) { row_start[base + i] = run; cursor[base + i] = run; }
        run += v[i];
    }
    if (b == 0 && tid == 0) row_start[N] = Ea;
}

__global__ void k_scatter(const int* __restrict__ ei, int E, int N,
                          int* cursor, int* colA) {
    int i = blockIdx.x * blockDim.x + threadIdx.x;
    int M = 2 * E + N;
    if (i >= M) return;
    int s, d;
    if (i < E)            { s = ei[i];         d = ei[E + i]; }
    else if (i < 2 * E)   { int j = i - E; s = ei[E + j]; d = ei[j]; }
    else                  { s = i - 2 * E;     d = s; }
    int pos = atomicAdd(&cursor[d], 1);
    colA[pos] = s;
}

// ---------------- projection GEMM + alpha ----------------
__global__ __launch_bounds__(256) void k_proj(
        const float* __restrict__ x, const float* __restrict__ W,
        const float* __restrict__ attn_src, const float* __restrict__ attn_dst,
        float* __restrict__ proj, float* __restrict__ asrc, float* __restrict__ adst,
        int N, int nbatch) {
    __shared__ float Wl[64 * CDIM];          // 32KB: half of W (64 k-rows)
    __shared__ float4 xs4[32][32];           // 16KB: 32 node rows as float4
    int tid = threadIdx.x;
    int g = tid >> 5, j = tid & 31;
    int h = j >> 3;

    for (int batch = blockIdx.x; batch < nbatch; batch += gridDim.x) {
        int base = batch * 32;
        __syncthreads();
        #pragma unroll
        for (int r = 0; r < 4; ++r) {
            int idx = tid + r * 256;
            int row = idx >> 5, kk = idx & 31;
            int n = base + row;
            float4 v = make_float4(0.f, 0.f, 0.f, 0.f);
            if (n < N) v = ((const float4*)x)[(size_t)n * 32 + kk];
            xs4[row][kk] = v;
        }
        float4 acc[4];
        #pragma unroll
        for (int m = 0; m < 4; ++m) acc[m] = make_float4(0.f, 0.f, 0.f, 0.f);

        for (int half = 0; half < 2; ++half) {
            __syncthreads();
            #pragma unroll
            for (int r = 0; r < 8; ++r) {
                int idx = tid + r * 256;
                ((float4*)Wl)[idx] = ((const float4*)W)[half * 2048 + idx];
            }
            __syncthreads();
            const float4* Wl4 = (const float4*)Wl;
            #pragma unroll
            for (int k4 = 0; k4 < 16; ++k4) {
                float4 w0 = Wl4[(k4 * 4 + 0) * 32 + j];
                float4 w1 = Wl4[(k4 * 4 + 1) * 32 + j];
                float4 w2 = Wl4[(k4 * 4 + 2) * 32 + j];
                float4 w3 = Wl4[(k4 * 4 + 3) * 32 + j];
                #pragma unroll
                for (int m = 0; m < 4; ++m) {
                    float4 xv = xs4[g * 4 + m][half * 16 + k4];
                    acc[m].x = fmaf(xv.x, w0.x, acc[m].x);
                    acc[m].y = fmaf(xv.x, w0.y, acc[m].y);
                    acc[m].z = fmaf(xv.x, w0.z, acc[m].z);
                    acc[m].w = fmaf(xv.x, w0.w, acc[m].w);
                    acc[m].x = fmaf(xv.y, w1.x, acc[m].x);
                    acc[m].y = fmaf(xv.y, w1.y, acc[m].y);
                    acc[m].z = fmaf(xv.y, w1.z, acc[m].z);
                    acc[m].w = fmaf(xv.y, w1.w, acc[m].w);
                    acc[m].x = fmaf(xv.z, w2.x, acc[m].x);
                    acc[m].y = fmaf(xv.z, w2.y, acc[m].y);
                    acc[m].z = fmaf(xv.z, w2.z, acc[m].z);
                    acc[m].w = fmaf(xv.z, w2.w, acc[m].w);
                    acc[m].x = fmaf(xv.w, w3.x, acc[m].x);
                    acc[m].y = fmaf(xv.w, w3.y, acc[m].y);
                    acc[m].z = fmaf(xv.w, w3.z, acc[m].z);
                    acc[m].w = fmaf(xv.w, w3.w, acc[m].w);
                }
            }
        }
        float4 as4 = ((const float4*)(attn_src + h * ODIM))[j & 7];
        float4 ad4 = ((const float4*)(attn_dst + h * ODIM))[j & 7];
        #pragma unroll
        for (int m = 0; m < 4; ++m) {
            int n = base + g * 4 + m;
            float ps = acc[m].x * as4.x + acc[m].y * as4.y + acc[m].z * as4.z + acc[m].w * as4.w;
            float pd = acc[m].x * ad4.x + acc[m].y * ad4.y + acc[m].z * ad4.z + acc[m].w * ad4.w;
            ps += __shfl_xor(ps, 1, 8); ps += __shfl_xor(ps, 2, 8); ps += __shfl_xor(ps, 4, 8);
            pd += __shfl_xor(pd, 1, 8); pd += __shfl_xor(pd, 2, 8); pd += __shfl_xor(pd, 4, 8);
            if (n < N) {
                ((float4*)proj)[(size_t)n * 32 + j] = acc[m];
                if ((j & 7) == 0) {
                    asrc[n * 4 + h] = ps;
                    adst[n * 4 + h] = pd;
                }
            }
        }
    }
}

// ---------------- gather / softmax / aggregate ----------------
// One 64-lane wave per node; lane owns cols {2*lane, 2*lane+1} (same head).
// Edge loop unrolled 8-wide with register-array prefetch for MLP.
__global__ __launch_bounds__(256) void k_gather(
        const float* __restrict__ proj, const float* __restrict__ asrc,
        const float* __restrict__ adst, const int* __restrict__ row_start,
        const int* __restrict__ colA, const float* __restrict__ bias,
        float* __restrict__ out, int N) {
    int node = blockIdx.x * 4 + (threadIdx.x >> 6);
    if (node >= N) return;
    int lane = threadIdx.x & 63;
    int h = lane >> 4;                 // col = 2*lane → head = lane/16
    float ad = adst[node * 4 + h];
    int beg = row_start[node];
    int end = row_start[node + 1];
    const float2* proj2 = (const float2*)proj;
    float denom = 0.f;
    float accx = 0.f, accy = 0.f;
    int e = beg;
    for (; e + 8 <= end; e += 8) {
        int s[8];
        float as[8];
        float2 p[8];
        #pragma unroll
        for (int i = 0; i < 8; ++i) s[i] = colA[e + i];
        #pragma unroll
        for (int i = 0; i < 8; ++i) as[i] = asrc[s[i] * 4 + h];
        #pragma unroll
        for (int i = 0; i < 8; ++i) p[i] = proj2[(size_t)s[i] * 64 + lane];
        #pragma unroll
        for (int i = 0; i < 8; ++i) {
            float scv = as[i] + ad;
            scv = (scv > 0.f) ? scv : 0.2f * scv;
            float ex = __expf(scv);
            denom += ex;
            accx = fmaf(ex, p[i].x, accx);
            accy = fmaf(ex, p[i].y, accy);
        }
    }
    for (; e < end; ++e) {
        int s = colA[e];
        float as = asrc[s * 4 + h];
        float scv = as + ad;
        scv = (scv > 0.f) ? scv : 0.2f * scv;
        float ex = __expf(scv);
        denom += ex;
        float2 p = proj2[(size_t)s * 64 + lane];
        accx = fmaf(ex, p.x, accx);
        accy = fmaf(ex, p.y, accy);
    }
    float inv = 1.f / denom;
    float2 b2 = ((const float2*)bias)[lane];
    float vx = accx * inv + b2.x;
    float vy = accy * inv + b2.y;
    vx = (vx > 0.f) ? vx : (__expf(vx) - 1.f);
    vy = (vy > 0.f) ? vy : (__expf(vy) - 1.f);
    ((float2*)out)[(size_t)node * 64 + lane] = make_float2(vx, vy);
}

extern "C" void kernel_launch(void* const* d_in, const int* in_sizes, int n_in,
                              void* d_out, int out_size, void* d_ws, size_t ws_size,
                              hipStream_t stream) {
    const float* x    = (const float*)d_in[0];
    const int*   ei   = (const int*)d_in[1];
    const float* W    = (const float*)d_in[2];
    const float* a_s  = (const float*)d_in[3];
    const float* a_d  = (const float*)d_in[4];
    const float* bias = (const float*)d_in[5];

    int N = in_sizes[0] / KDIM;
    int E = in_sizes[1] / 2;
    int Ea = 2 * E + N;

    char* ws = (char*)d_ws;
    size_t off = 0;
    auto alloc = [&](size_t bytes) -> void* {
        void* p = ws + off;
        off = (off + bytes + 255) & ~(size_t)255;
        return p;
    };
    float* proj      = (float*)alloc((size_t)N * CDIM * 4);
    float* asrc      = (float*)alloc((size_t)N * NHEADS * 4);
    float* adst      = (float*)alloc((size_t)N * NHEADS * 4);
    int*   counts    = (int*)alloc((size_t)N * 4);
    int*   row_start = (int*)alloc((size_t)(N + 1) * 4);
    int*   cursor    = (int*)alloc((size_t)N * 4);
    int*   bsums     = (int*)alloc(4096);
    int*   colA      = (int*)alloc((size_t)Ea * 4);

    int NB = (N + 1023) / 1024;
    int nbatch = (N + 31) / 32;

    k_init_counts<<<(N + 255) / 256, 256, 0, stream>>>(counts, N);
    k_count<<<(E + 255) / 256, 256, 0, stream>>>(ei, E, counts);
    k_bsum<<<NB, 256, 0, stream>>>(counts, bsums, N);
    k_tops<<<1, 64, 0, stream>>>(bsums, NB);
    k_scan_add<<<NB, 256, 0, stream>>>(counts, bsums, row_start, cursor, N, Ea);
    k_scatter<<<(2 * E + N + 255) / 256, 256, 0, stream>>>(ei, E, N, cursor, colA);
    k_proj<<<768, 256, 0, stream>>>(x, W, a_s, a_d, proj, asrc, adst, N, nbatch);
    k_gather<<<(N + 3) / 4, 256, 0, stream>>>(proj, asrc, adst, row_start, colA, bias,
                                              (float*)d_out, N);
}

// Round 3
// 217.279 us; speedup vs baseline: 2.5591x; 1.6858x over previous
//
#include <hip/hip_runtime.h>
#include <hip/hip_bf16.h>

#define NHEADS 4
#define ODIM 32
#define CDIM 128   // NHEADS*ODIM
#define KDIM 128   // IN_DIM

static __device__ __forceinline__ unsigned short f2bf(float f) {
    unsigned u = __float_as_uint(f);
    unsigned r = (u + 0x7FFF + ((u >> 16) & 1)) >> 16;   // RNE
    return (unsigned short)r;
}
static __device__ __forceinline__ float bf2f(unsigned short b) {
    return __uint_as_float(((unsigned)b) << 16);
}

// ---------------- CSR build ----------------

__global__ void k_init_counts(int* counts, int N) {
    int i = blockIdx.x * blockDim.x + threadIdx.x;
    if (i < N) counts[i] = 1;   // self loop reserves slot 0
}

// counts + per-directed-edge rank (old value of the atomic)
__global__ void k_count_rank(const int* __restrict__ ei, int E, int* counts,
                             int* __restrict__ rnk) {
    int i = blockIdx.x * blockDim.x + threadIdx.x;
    if (i < E) {
        int s0 = ei[i], d0 = ei[E + i];
        int r0 = atomicAdd(&counts[d0], 1);   // edge s0 -> d0 lives in row d0
        int r1 = atomicAdd(&counts[s0], 1);   // reverse edge in row s0
        rnk[i] = r0;
        rnk[E + i] = r1;
    }
}

__global__ void k_bsum(const int* __restrict__ counts, int* bsums, int N) {
    __shared__ int ws[4];
    int tid = threadIdx.x;
    int base = blockIdx.x * 1024 + tid * 4;
    int s = 0;
    #pragma unroll
    for (int i = 0; i < 4; ++i) s += (base + i < N) ? counts[base + i] : 0;
    #pragma unroll
    for (int off = 1; off < 64; off <<= 1) s += __shfl_xor(s, off, 64);
    if ((tid & 63) == 0) ws[tid >> 6] = s;
    __syncthreads();
    if (tid == 0) bsums[blockIdx.x] = ws[0] + ws[1] + ws[2] + ws[3];
}

__global__ void k_tops(int* bsums, int NB) {
    if (threadIdx.x == 0) {
        int run = 0;
        for (int i = 0; i < NB; ++i) { int t = bsums[i]; bsums[i] = run; run += t; }
    }
}

// row_start + write self-loop entries (slot 0 of each row)
__global__ void k_scan_add(const int* __restrict__ counts, const int* __restrict__ btops,
                           int* row_start, int* colA, int N, int Ea) {
    __shared__ int wsum[4];
    int tid = threadIdx.x;
    int b = blockIdx.x;
    int base = b * 1024 + tid * 4;
    int v[4];
    #pragma unroll
    for (int i = 0; i < 4; ++i) v[i] = (base + i < N) ? counts[base + i] : 0;
    int tsum = v[0] + v[1] + v[2] + v[3];
    int lane = tid & 63, w = tid >> 6;
    int sc = tsum;
    #pragma unroll
    for (int off = 1; off < 64; off <<= 1) {
        int o = __shfl_up(sc, off, 64);
        if (lane >= off) sc += o;
    }
    if (lane == 63) wsum[w] = sc;
    __syncthreads();
    int woff = 0;
    for (int i = 0; i < w; ++i) woff += wsum[i];
    int run = btops[b] + woff + (sc - tsum);
    #pragma unroll
    for (int i = 0; i < 4; ++i) {
        if (base + i < N) {
            row_start[base + i] = run;
            colA[run] = base + i;      // self loop at slot 0
        }
        run += v[i];
    }
    if (b == 0 && tid == 0) row_start[N] = Ea;
}

// atomic-free scatter: position = row_start[dst] + saved rank
__global__ void k_scatter_rank(const int* __restrict__ ei, int E,
                               const int* __restrict__ rnk,
                               const int* __restrict__ row_start,
                               int* __restrict__ colA) {
    int i = blockIdx.x * blockDim.x + threadIdx.x;
    if (i < E) {
        int s0 = ei[i], d0 = ei[E + i];
        colA[row_start[d0] + rnk[i]] = s0;
        colA[row_start[s0] + rnk[E + i]] = d0;
    }
}

// ---------------- projection GEMM + alpha (bf16 proj out) ----------------
__global__ __launch_bounds__(256) void k_proj(
        const float* __restrict__ x, const float* __restrict__ W,
        const float* __restrict__ attn_src, const float* __restrict__ attn_dst,
        unsigned short* __restrict__ proj, float* __restrict__ asrc, float* __restrict__ adst,
        int N, int nbatch) {
    __shared__ float Wl[64 * CDIM];          // 32KB: half of W (64 k-rows)
    __shared__ float4 xs4[32][32];           // 16KB: 32 node rows as float4
    int tid = threadIdx.x;
    int g = tid >> 5, j = tid & 31;
    int h = j >> 3;

    for (int batch = blockIdx.x; batch < nbatch; batch += gridDim.x) {
        int base = batch * 32;
        __syncthreads();
        #pragma unroll
        for (int r = 0; r < 4; ++r) {
            int idx = tid + r * 256;
            int row = idx >> 5, kk = idx & 31;
            int n = base + row;
            float4 v = make_float4(0.f, 0.f, 0.f, 0.f);
            if (n < N) v = ((const float4*)x)[(size_t)n * 32 + kk];
            xs4[row][kk] = v;
        }
        float4 acc[4];
        #pragma unroll
        for (int m = 0; m < 4; ++m) acc[m] = make_float4(0.f, 0.f, 0.f, 0.f);

        for (int half = 0; half < 2; ++half) {
            __syncthreads();
            #pragma unroll
            for (int r = 0; r < 8; ++r) {
                int idx = tid + r * 256;
                ((float4*)Wl)[idx] = ((const float4*)W)[half * 2048 + idx];
            }
            __syncthreads();
            const float4* Wl4 = (const float4*)Wl;
            #pragma unroll
            for (int k4 = 0; k4 < 16; ++k4) {
                float4 w0 = Wl4[(k4 * 4 + 0) * 32 + j];
                float4 w1 = Wl4[(k4 * 4 + 1) * 32 + j];
                float4 w2 = Wl4[(k4 * 4 + 2) * 32 + j];
                float4 w3 = Wl4[(k4 * 4 + 3) * 32 + j];
                #pragma unroll
                for (int m = 0; m < 4; ++m) {
                    float4 xv = xs4[g * 4 + m][half * 16 + k4];
                    acc[m].x = fmaf(xv.x, w0.x, acc[m].x);
                    acc[m].y = fmaf(xv.x, w0.y, acc[m].y);
                    acc[m].z = fmaf(xv.x, w0.z, acc[m].z);
                    acc[m].w = fmaf(xv.x, w0.w, acc[m].w);
                    acc[m].x = fmaf(xv.y, w1.x, acc[m].x);
                    acc[m].y = fmaf(xv.y, w1.y, acc[m].y);
                    acc[m].z = fmaf(xv.y, w1.z, acc[m].z);
                    acc[m].w = fmaf(xv.y, w1.w, acc[m].w);
                    acc[m].x = fmaf(xv.z, w2.x, acc[m].x);
                    acc[m].y = fmaf(xv.z, w2.y, acc[m].y);
                    acc[m].z = fmaf(xv.z, w2.z, acc[m].z);
                    acc[m].w = fmaf(xv.z, w2.w, acc[m].w);
                    acc[m].x = fmaf(xv.w, w3.x, acc[m].x);
                    acc[m].y = fmaf(xv.w, w3.y, acc[m].y);
                    acc[m].z = fmaf(xv.w, w3.z, acc[m].z);
                    acc[m].w = fmaf(xv.w, w3.w, acc[m].w);
                }
            }
        }
        float4 as4 = ((const float4*)(attn_src + h * ODIM))[j & 7];
        float4 ad4 = ((const float4*)(attn_dst + h * ODIM))[j & 7];
        #pragma unroll
        for (int m = 0; m < 4; ++m) {
            int n = base + g * 4 + m;
            float ps = acc[m].x * as4.x + acc[m].y * as4.y + acc[m].z * as4.z + acc[m].w * as4.w;
            float pd = acc[m].x * ad4.x + acc[m].y * ad4.y + acc[m].z * ad4.z + acc[m].w * ad4.w;
            ps += __shfl_xor(ps, 1, 8); ps += __shfl_xor(ps, 2, 8); ps += __shfl_xor(ps, 4, 8);
            pd += __shfl_xor(pd, 1, 8); pd += __shfl_xor(pd, 2, 8); pd += __shfl_xor(pd, 4, 8);
            if (n < N) {
                ushort4 pb;
                pb.x = f2bf(acc[m].x); pb.y = f2bf(acc[m].y);
                pb.z = f2bf(acc[m].z); pb.w = f2bf(acc[m].w);
                ((ushort4*)proj)[(size_t)n * 32 + j] = pb;
                if ((j & 7) == 0) {
                    asrc[n * 4 + h] = ps;
                    adst[n * 4 + h] = pd;
                }
            }
        }
    }
}

// ---------------- gather / softmax / aggregate ----------------
// One 64-lane wave per node; lane owns cols {2*lane, 2*lane+1}; bf16 proj rows.
__global__ __launch_bounds__(256) void k_gather(
        const unsigned short* __restrict__ proj, const float* __restrict__ asrc,
        const float* __restrict__ adst, const int* __restrict__ row_start,
        const int* __restrict__ colA, const float* __restrict__ bias,
        float* __restrict__ out, int N) {
    int node = blockIdx.x * 4 + (threadIdx.x >> 6);
    if (node >= N) return;
    int lane = threadIdx.x & 63;
    int h = lane >> 4;                 // col = 2*lane → head = lane/16
    float ad = adst[node * 4 + h];
    int beg = row_start[node];
    int end = row_start[node + 1];
    const ushort2* proj2 = (const ushort2*)proj;
    float denom = 0.f;
    float accx = 0.f, accy = 0.f;
    int e = beg;
    for (; e + 8 <= end; e += 8) {
        int s[8];
        float as[8];
        ushort2 p[8];
        #pragma unroll
        for (int i = 0; i < 8; ++i) s[i] = colA[e + i];
        #pragma unroll
        for (int i = 0; i < 8; ++i) as[i] = asrc[s[i] * 4 + h];
        #pragma unroll
        for (int i = 0; i < 8; ++i) p[i] = proj2[(size_t)s[i] * 64 + lane];
        #pragma unroll
        for (int i = 0; i < 8; ++i) {
            float scv = as[i] + ad;
            scv = (scv > 0.f) ? scv : 0.2f * scv;
            float ex = __expf(scv);
            denom += ex;
            accx = fmaf(ex, bf2f(p[i].x), accx);
            accy = fmaf(ex, bf2f(p[i].y), accy);
        }
    }
    for (; e < end; ++e) {
        int s = colA[e];
        float as = asrc[s * 4 + h];
        float scv = as + ad;
        scv = (scv > 0.f) ? scv : 0.2f * scv;
        float ex = __expf(scv);
        denom += ex;
        ushort2 p = proj2[(size_t)s * 64 + lane];
        accx = fmaf(ex, bf2f(p.x), accx);
        accy = fmaf(ex, bf2f(p.y), accy);
    }
    float inv = 1.f / denom;
    float2 b2 = ((const float2*)bias)[lane];
    float vx = accx * inv + b2.x;
    float vy = accy * inv + b2.y;
    vx = (vx > 0.f) ? vx : (__expf(vx) - 1.f);
    vy = (vy > 0.f) ? vy : (__expf(vy) - 1.f);
    ((float2*)out)[(size_t)node * 64 + lane] = make_float2(vx, vy);
}

extern "C" void kernel_launch(void* const* d_in, const int* in_sizes, int n_in,
                              void* d_out, int out_size, void* d_ws, size_t ws_size,
                              hipStream_t stream) {
    const float* x    = (const float*)d_in[0];
    const int*   ei   = (const int*)d_in[1];
    const float* W    = (const float*)d_in[2];
    const float* a_s  = (const float*)d_in[3];
    const float* a_d  = (const float*)d_in[4];
    const float* bias = (const float*)d_in[5];

    int N = in_sizes[0] / KDIM;
    int E = in_sizes[1] / 2;
    int Ea = 2 * E + N;

    char* ws = (char*)d_ws;
    size_t off = 0;
    auto alloc = [&](size_t bytes) -> void* {
        void* p = ws + off;
        off = (off + bytes + 255) & ~(size_t)255;
        return p;
    };
    unsigned short* proj = (unsigned short*)alloc((size_t)N * CDIM * 2);
    float* asrc      = (float*)alloc((size_t)N * NHEADS * 4);
    float* adst      = (float*)alloc((size_t)N * NHEADS * 4);
    int*   counts    = (int*)alloc((size_t)N * 4);
    int*   row_start = (int*)alloc((size_t)(N + 1) * 4);
    int*   rnk       = (int*)alloc((size_t)2 * E * 4);
    int*   bsums     = (int*)alloc(4096);
    int*   colA      = (int*)alloc((size_t)Ea * 4);

    int NB = (N + 1023) / 1024;
    int nbatch = (N + 31) / 32;

    k_init_counts<<<(N + 255) / 256, 256, 0, stream>>>(counts, N);
    k_count_rank<<<(E + 255) / 256, 256, 0, stream>>>(ei, E, counts, rnk);
    k_bsum<<<NB, 256, 0, stream>>>(counts, bsums, N);
    k_tops<<<1, 64, 0, stream>>>(bsums, NB);
    k_scan_add<<<NB, 256, 0, stream>>>(counts, bsums, row_start, colA, N, Ea);
    k_scatter_rank<<<(E + 255) / 256, 256, 0, stream>>>(ei, E, rnk, row_start, colA);
    k_proj<<<768, 256, 0, stream>>>(x, W, a_s, a_d, proj, asrc, adst, N, nbatch);
    k_gather<<<(N + 3) / 4, 256, 0, stream>>>(proj, asrc, adst, row_start, colA, bias,
                                              (float*)d_out, N);
}